// Round 1
// baseline (531.509 us; speedup 1.0000x reference)
//
#include <hip/hip_runtime.h>
#include <hip/hip_bf16.h>
#include <stdint.h>

#define N_NODES 100000
#define N_EDGES 1600000
#define D 128

__device__ __forceinline__ unsigned short f2bf(float f) {
    unsigned u = __float_as_uint(f);
    unsigned r = (u + 0x7fffu + ((u >> 16) & 1u)) >> 16;   // RNE
    return (unsigned short)r;
}

// ---------------- K0: zero cursor (counts) + stats ----------------
__global__ __launch_bounds__(256) void k_zero(unsigned* cursor, float* stats) {
    int i = blockIdx.x * 256 + threadIdx.x;
    if (i < N_NODES) cursor[i] = 0u;
    if (blockIdx.x == 0) stats[threadIdx.x] = 0.f;   // 256 floats: sum, sumsq
}

// ---------------- K1: histogram of edge_row ----------------
__global__ __launch_bounds__(256) void k_hist(const int* __restrict__ row, unsigned* cursor) {
    int i = blockIdx.x * 256 + threadIdx.x;
    int stride = gridDim.x * 256;
    for (int e = i; e < N_EDGES; e += stride)
        atomicAdd(&cursor[row[e]], 1u);
}

// ---------------- K2a: per-block sums for scan ----------------
__global__ __launch_bounds__(512) void k_scan_bsum(const unsigned* __restrict__ counts, unsigned* bsums) {
    __shared__ unsigned lds[512];
    int t = threadIdx.x;
    int g = blockIdx.x * 512 + t;
    lds[t] = (g < N_NODES) ? counts[g] : 0u;
    __syncthreads();
    for (int off = 256; off > 0; off >>= 1) {
        if (t < off) lds[t] += lds[t + off];
        __syncthreads();
    }
    if (t == 0) bsums[blockIdx.x] = lds[0];
}

// ---------------- K2b: exclusive scan of block sums (1 block) ----------------
__global__ __launch_bounds__(256) void k_scan_top(unsigned* bsums, int nb) {
    __shared__ unsigned lds[256];
    int t = threadIdx.x;
    lds[t] = (t < nb) ? bsums[t] : 0u;
    __syncthreads();
    for (int off = 1; off < 256; off <<= 1) {
        unsigned add = (t >= off) ? lds[t - off] : 0u;
        __syncthreads();
        lds[t] += add;
        __syncthreads();
    }
    if (t < nb) bsums[t] = (t == 0) ? 0u : lds[t - 1];
}

// ---------------- K2c: per-chunk exclusive scan + offset -> row_ptr, cursor ----------------
__global__ __launch_bounds__(512) void k_scan_apply(const unsigned* __restrict__ counts,
                                                    const unsigned* __restrict__ bsums,
                                                    unsigned* row_ptr, unsigned* cursor) {
    __shared__ unsigned lds[512];
    int t = threadIdx.x;
    int g = blockIdx.x * 512 + t;
    unsigned v = (g < N_NODES) ? counts[g] : 0u;
    lds[t] = v;
    __syncthreads();
    for (int off = 1; off < 512; off <<= 1) {
        unsigned add = (t >= off) ? lds[t - off] : 0u;
        __syncthreads();
        lds[t] += add;
        __syncthreads();
    }
    unsigned excl = ((t == 0) ? 0u : lds[t - 1]) + bsums[blockIdx.x];
    if (g < N_NODES) { row_ptr[g] = excl; cursor[g] = excl; }
    if (g == 0) row_ptr[N_NODES] = N_EDGES;
}

// ---------------- K3: fill per-node edge buckets ----------------
__global__ __launch_bounds__(256) void k_fill(const int* __restrict__ row, const int* __restrict__ col,
                                              const float* __restrict__ w, unsigned* cursor,
                                              uint2* __restrict__ edata) {
    int i = blockIdx.x * 256 + threadIdx.x;
    int stride = gridDim.x * 256;
    for (int e = i; e < N_EDGES; e += stride) {
        int r = row[e];
        unsigned pos = atomicAdd(&cursor[r], 1u);
        edata[pos] = make_uint2((unsigned)col[e], __float_as_uint(w[e]));
    }
}

// ---------------- K5: GEMM  z = x@W[0:128] (bf16), v = x@W[128:256]+b (-> d_out) ----------------
#define GM_MT 64
__global__ __launch_bounds__(256) void k_gemm(const float* __restrict__ x, const float* __restrict__ W,
                                              const float* __restrict__ b,
                                              unsigned short* __restrict__ z, float* __restrict__ out) {
    __shared__ float xs[GM_MT * 128];   // [m][k]  32KB
    __shared__ float ws[32 * 256];      // chunk [k][j] 32KB
    int tid = threadIdx.x;
    int m0 = blockIdx.x * GM_MT;

    // stage x tile (coalesced float4, linear LDS -> no conflicts)
    #pragma unroll
    for (int q = 0; q < 8; ++q) {
        int idx = q * 256 + tid;           // 2048 float4
        int m = idx >> 5;                  // 32 float4 per row
        int k4 = (idx & 31) * 4;
        float4 v = (m0 + m < N_NODES) ? *(const float4*)(x + (size_t)(m0 + m) * 128 + k4)
                                      : make_float4(0.f, 0.f, 0.f, 0.f);
        *(float4*)(xs + m * 128 + k4) = v;
    }

    int tn = tid & 63;   // col group, n0 = tn*4  (cols 0..255)
    int tm = tid >> 6;   // row group, rows tm*16 .. +15
    int n0 = tn * 4;

    float acc[16][4];
    #pragma unroll
    for (int r = 0; r < 16; ++r)
        #pragma unroll
        for (int c = 0; c < 4; ++c) acc[r][c] = 0.f;

    for (int kc = 0; kc < 128; kc += 32) {
        __syncthreads();
        // stage Bcat chunk: Bcat[k][j] = j<128 ? W[k][j] : W[128+k][j-128]
        #pragma unroll
        for (int q = 0; q < 8; ++q) {
            int idx = q * 256 + tid;       // 2048 float4
            int kl = idx >> 6;             // 64 float4 per 256-col row
            int j4 = (idx & 63) * 4;
            const float* src = (j4 < 128) ? (W + (size_t)(kc + kl) * 128 + j4)
                                          : (W + (size_t)(128 + kc + kl) * 128 + (j4 - 128));
            *(float4*)(ws + kl * 256 + j4) = *(const float4*)src;
        }
        __syncthreads();
        #pragma unroll 4
        for (int kl = 0; kl < 32; ++kl) {
            float4 wv = *(const float4*)(ws + kl * 256 + n0);
            #pragma unroll
            for (int r = 0; r < 16; ++r) {
                float xv = xs[(tm * 16 + r) * 128 + kc + kl];   // wave-uniform broadcast
                acc[r][0] += xv * wv.x;
                acc[r][1] += xv * wv.y;
                acc[r][2] += xv * wv.z;
                acc[r][3] += xv * wv.w;
            }
        }
    }

    if (tn < 32) {   // z part, cols n0..n0+3
        #pragma unroll
        for (int r = 0; r < 16; ++r) {
            int m = m0 + tm * 16 + r;
            if (m < N_NODES) {
                ushort4 pk;
                pk.x = f2bf(acc[r][0]); pk.y = f2bf(acc[r][1]);
                pk.z = f2bf(acc[r][2]); pk.w = f2bf(acc[r][3]);
                *(ushort4*)(z + (size_t)m * 128 + n0) = pk;
            }
        }
    } else {         // v part, cols jc..jc+3 -> d_out
        int jc = n0 - 128;
        float4 bb = *(const float4*)(b + jc);
        #pragma unroll
        for (int r = 0; r < 16; ++r) {
            int m = m0 + tm * 16 + r;
            if (m < N_NODES) {
                float4 o;
                o.x = acc[r][0] + bb.x; o.y = acc[r][1] + bb.y;
                o.z = acc[r][2] + bb.z; o.w = acc[r][3] + bb.w;
                *(float4*)(out + (size_t)m * 128 + jc) = o;
            }
        }
    }
}

// ---------------- K4: wave-per-node aggregation  out[i] = sum w_e * z[col_e] + v[i] ----------------
__global__ __launch_bounds__(256) void k_agg(const unsigned* __restrict__ row_ptr,
                                             const uint2* __restrict__ edata,
                                             const unsigned short* __restrict__ z,
                                             float* __restrict__ out) {
    int node = blockIdx.x * 4 + (threadIdx.x >> 6);
    int lane = threadIdx.x & 63;
    int d0 = lane * 2;
    unsigned beg = row_ptr[node], end = row_ptr[node + 1];
    float a0 = 0.f, a1 = 0.f;
    for (unsigned j = beg; j < end; ++j) {
        uint2 ed = edata[j];                       // wave-uniform broadcast
        float w = __uint_as_float(ed.y);
        unsigned zz = *(const unsigned*)(z + (size_t)ed.x * 128 + d0);  // 2 bf16, coalesced
        a0 += w * __uint_as_float(zz << 16);
        a1 += w * __uint_as_float(zz & 0xffff0000u);
    }
    size_t o = (size_t)node * 128 + d0;
    float2 v = *(const float2*)(out + o);
    *(float2*)(out + o) = make_float2(a0 + v.x, a1 + v.y);
}

// ---------------- K6: column sums / sumsq ----------------
__global__ __launch_bounds__(256) void k_stats(const float* __restrict__ out, float* stats) {
    int c = threadIdx.x & 127;
    int rbase = blockIdx.x * 2 + (threadIdx.x >> 7);
    float s = 0.f, q = 0.f;
    for (int r = rbase; r < N_NODES; r += gridDim.x * 2) {
        float v = out[(size_t)r * 128 + c];
        s += v; q += v * v;
    }
    __shared__ float lds[256];
    lds[threadIdx.x] = s;
    __syncthreads();
    if (threadIdx.x < 128) atomicAdd(&stats[c], lds[threadIdx.x] + lds[threadIdx.x + 128]);
    __syncthreads();
    lds[threadIdx.x] = q;
    __syncthreads();
    if (threadIdx.x < 128) atomicAdd(&stats[128 + c], lds[threadIdx.x] + lds[threadIdx.x + 128]);
}

// ---------------- K7: BN scale/shift ----------------
__global__ __launch_bounds__(128) void k_finalize(const float* __restrict__ stats,
                                                  const float* __restrict__ gamma,
                                                  const float* __restrict__ beta, float* ss) {
    int c = threadIdx.x;
    float mean = stats[c] * (1.f / N_NODES);
    float var  = stats[128 + c] * (1.f / N_NODES) - mean * mean;
    float sc = gamma[c] / sqrtf(var + 1e-5f);
    ss[c] = sc;
    ss[128 + c] = beta[c] - mean * sc;
}

// ---------------- K8: apply BN + ReLU (in place, float4) ----------------
__global__ __launch_bounds__(256) void k_apply(float* __restrict__ out, const float* __restrict__ ss) {
    __shared__ float s_sc[128], s_sh[128];
    if (threadIdx.x < 128) { s_sc[threadIdx.x] = ss[threadIdx.x]; s_sh[threadIdx.x] = ss[128 + threadIdx.x]; }
    __syncthreads();
    int idx = blockIdx.x * 256 + threadIdx.x;
    int total = N_NODES * 128 / 4;
    int stride = gridDim.x * 256;
    for (int i = idx; i < total; i += stride) {
        float4 v = ((const float4*)out)[i];
        int c = (i * 4) & 127;
        v.x = fmaxf(0.f, v.x * s_sc[c]     + s_sh[c]);
        v.y = fmaxf(0.f, v.y * s_sc[c + 1] + s_sh[c + 1]);
        v.z = fmaxf(0.f, v.z * s_sc[c + 2] + s_sh[c + 2]);
        v.w = fmaxf(0.f, v.w * s_sc[c + 3] + s_sh[c + 3]);
        ((float4*)out)[i] = v;
    }
}

extern "C" void kernel_launch(void* const* d_in, const int* in_sizes, int n_in,
                              void* d_out, int out_size, void* d_ws, size_t ws_size,
                              hipStream_t stream) {
    (void)in_sizes; (void)n_in; (void)out_size; (void)ws_size;
    const float* x      = (const float*)d_in[0];
    const float* edge_w = (const float*)d_in[1];
    const float* W      = (const float*)d_in[2];
    const float* b      = (const float*)d_in[3];
    const float* gamma  = (const float*)d_in[4];
    const float* beta   = (const float*)d_in[5];
    const int*   erow   = (const int*)d_in[6];
    const int*   ecol   = (const int*)d_in[7];
    float* out = (float*)d_out;

    uint8_t* ws = (uint8_t*)d_ws;
    unsigned* row_ptr = (unsigned*)(ws + 0);                     // (N+1)*4
    unsigned* cursor  = (unsigned*)(ws + 400128);                // N*4
    uint2*    edata   = (uint2*)(ws + 800256);                   // E*8
    unsigned short* z = (unsigned short*)(ws + 13600256);        // N*128*2
    float*    stats   = (float*)(ws + 39200256);                 // 256 f
    float*    ss      = (float*)(ws + 39201280);                 // 256 f
    unsigned* bsums   = (unsigned*)(ws + 39202304);              // 196*4

    const int NB_SCAN = (N_NODES + 511) / 512;   // 196

    hipLaunchKernelGGL(k_zero, dim3((N_NODES + 255) / 256), dim3(256), 0, stream, cursor, stats);
    hipLaunchKernelGGL(k_hist, dim3(2048), dim3(256), 0, stream, erow, cursor);
    hipLaunchKernelGGL(k_scan_bsum, dim3(NB_SCAN), dim3(512), 0, stream, cursor, bsums);
    hipLaunchKernelGGL(k_scan_top, dim3(1), dim3(256), 0, stream, bsums, NB_SCAN);
    hipLaunchKernelGGL(k_scan_apply, dim3(NB_SCAN), dim3(512), 0, stream, cursor, bsums, row_ptr, cursor);
    hipLaunchKernelGGL(k_fill, dim3(2048), dim3(256), 0, stream, erow, ecol, edge_w, cursor, edata);
    hipLaunchKernelGGL(k_gemm, dim3((N_NODES + GM_MT - 1) / GM_MT), dim3(256), 0, stream, x, W, b, z, out);
    hipLaunchKernelGGL(k_agg, dim3(N_NODES / 4), dim3(256), 0, stream, row_ptr, edata, z, out);
    hipLaunchKernelGGL(k_stats, dim3(1024), dim3(256), 0, stream, out, stats);
    hipLaunchKernelGGL(k_finalize, dim3(1), dim3(128), 0, stream, stats, gamma, beta, ss);
    hipLaunchKernelGGL(k_apply, dim3(2048), dim3(256), 0, stream, out, ss);
}

// Round 2
// 387.254 us; speedup vs baseline: 1.3725x; 1.3725x over previous
//
#include <hip/hip_runtime.h>
#include <hip/hip_bf16.h>
#include <stdint.h>

#define N_NODES 100000
#define N_EDGES 1600000
#define D 128

typedef __attribute__((ext_vector_type(8))) __bf16 bf16x8;
typedef __attribute__((ext_vector_type(4))) float f32x4;

__device__ __forceinline__ unsigned short f2bf(float f) {
    unsigned u = __float_as_uint(f);
    unsigned r = (u + 0x7fffu + ((u >> 16) & 1u)) >> 16;   // RNE
    return (unsigned short)r;
}
__device__ __forceinline__ unsigned pack2bf(float a, float b) {
    return (unsigned)f2bf(a) | ((unsigned)f2bf(b) << 16);
}

// ---------------- K0: zero cursor (counts) + stats ----------------
__global__ __launch_bounds__(256) void k_zero(unsigned* cursor, float* stats) {
    int i = blockIdx.x * 256 + threadIdx.x;
    if (i < N_NODES) cursor[i] = 0u;
    if (blockIdx.x == 0) stats[threadIdx.x] = 0.f;   // 256 floats: sum, sumsq
}

// ---------------- K1: histogram of edge_row ----------------
__global__ __launch_bounds__(256) void k_hist(const int* __restrict__ row, unsigned* cursor) {
    int i = blockIdx.x * 256 + threadIdx.x;
    int stride = gridDim.x * 256;
    for (int e = i; e < N_EDGES; e += stride)
        atomicAdd(&cursor[row[e]], 1u);
}

// ---------------- K2a: per-block sums for scan ----------------
__global__ __launch_bounds__(512) void k_scan_bsum(const unsigned* __restrict__ counts, unsigned* bsums) {
    __shared__ unsigned lds[512];
    int t = threadIdx.x;
    int g = blockIdx.x * 512 + t;
    lds[t] = (g < N_NODES) ? counts[g] : 0u;
    __syncthreads();
    for (int off = 256; off > 0; off >>= 1) {
        if (t < off) lds[t] += lds[t + off];
        __syncthreads();
    }
    if (t == 0) bsums[blockIdx.x] = lds[0];
}

// ---------------- K2b: exclusive scan of block sums (1 block) ----------------
__global__ __launch_bounds__(256) void k_scan_top(unsigned* bsums, int nb) {
    __shared__ unsigned lds[256];
    int t = threadIdx.x;
    lds[t] = (t < nb) ? bsums[t] : 0u;
    __syncthreads();
    for (int off = 1; off < 256; off <<= 1) {
        unsigned add = (t >= off) ? lds[t - off] : 0u;
        __syncthreads();
        lds[t] += add;
        __syncthreads();
    }
    if (t < nb) bsums[t] = (t == 0) ? 0u : lds[t - 1];
}

// ---------------- K2c: per-chunk exclusive scan + offset -> row_ptr, cursor ----------------
__global__ __launch_bounds__(512) void k_scan_apply(const unsigned* __restrict__ counts,
                                                    const unsigned* __restrict__ bsums,
                                                    unsigned* row_ptr, unsigned* cursor) {
    __shared__ unsigned lds[512];
    int t = threadIdx.x;
    int g = blockIdx.x * 512 + t;
    unsigned v = (g < N_NODES) ? counts[g] : 0u;
    lds[t] = v;
    __syncthreads();
    for (int off = 1; off < 512; off <<= 1) {
        unsigned add = (t >= off) ? lds[t - off] : 0u;
        __syncthreads();
        lds[t] += add;
        __syncthreads();
    }
    unsigned excl = ((t == 0) ? 0u : lds[t - 1]) + bsums[blockIdx.x];
    if (g < N_NODES) { row_ptr[g] = excl; cursor[g] = excl; }
    if (g == 0) row_ptr[N_NODES] = N_EDGES;
}

// ---------------- K3: fill per-node edge buckets ----------------
__global__ __launch_bounds__(256) void k_fill(const int* __restrict__ row, const int* __restrict__ col,
                                              const float* __restrict__ w, unsigned* cursor,
                                              uint2* __restrict__ edata) {
    int i = blockIdx.x * 256 + threadIdx.x;
    int stride = gridDim.x * 256;
    for (int e = i; e < N_EDGES; e += stride) {
        int r = row[e];
        unsigned pos = atomicAdd(&cursor[r], 1u);
        edata[pos] = make_uint2((unsigned)col[e], __float_as_uint(w[e]));
    }
}

// ---------------- Kp: W -> Wt bf16 [n=256][k=128]  (runs after k_fill, reuses cursor space) ----
__global__ __launch_bounds__(256) void k_prep(const float* __restrict__ W, unsigned short* __restrict__ Wt) {
    int i = blockIdx.x * 256 + threadIdx.x;   // 32768
    int n = i >> 7, k = i & 127;
    float v = (n < 128) ? W[(size_t)k * 128 + n] : W[(size_t)(128 + k) * 128 + (n - 128)];
    Wt[i] = f2bf(v);
}

// ---------------- K5: MFMA GEMM  z = bf16(x@W_top), out = x@W_bot + b ----------------
// block: 64 rows x 256 cols, K=128. 4 waves; wave w -> cols [w*64, w*64+64).
__global__ __launch_bounds__(256) void k_gemm(const float* __restrict__ x,
                                              const unsigned short* __restrict__ Wt,
                                              const float* __restrict__ b,
                                              unsigned short* __restrict__ z,
                                              float* __restrict__ out) {
    __shared__ unsigned short xs[64 * 128];   // bf16, XOR-swizzled, 16KB
    int tid = threadIdx.x;
    int lane = tid & 63;
    int wv = tid >> 6;
    int m0 = blockIdx.x * 64;
    int row_in = lane & 15;
    int kg = lane >> 4;        // 0..3

    // ---- stage x tile as bf16 into LDS (swizzled: byte ^= (row&7)<<4) ----
    #pragma unroll
    for (int q = 0; q < 4; ++q) {
        int c = q * 256 + tid;          // 1024 chunks of 8 bf16
        int row = c >> 4;
        int kc = (c & 15) * 8;
        float4 v0, v1;
        int gr = m0 + row;
        if (gr < N_NODES) {
            v0 = *(const float4*)(x + (size_t)gr * 128 + kc);
            v1 = *(const float4*)(x + (size_t)gr * 128 + kc + 4);
        } else {
            v0 = make_float4(0.f, 0.f, 0.f, 0.f);
            v1 = v0;
        }
        uint4 p;
        p.x = pack2bf(v0.x, v0.y); p.y = pack2bf(v0.z, v0.w);
        p.z = pack2bf(v1.x, v1.y); p.w = pack2bf(v1.z, v1.w);
        unsigned off = (unsigned)row * 256u + (((unsigned)kc * 2u) ^ (((unsigned)row & 7u) << 4));
        *(uint4*)((char*)xs + off) = p;
    }

    // ---- B fragments -> registers (from Wt, L2-resident) ----
    bf16x8 Bf[4][4];   // [nf][ks]
    {
        int col = wv * 64 + row_in;
        #pragma unroll
        for (int nf = 0; nf < 4; ++nf)
            #pragma unroll
            for (int ks = 0; ks < 4; ++ks)
                Bf[nf][ks] = *(const bf16x8*)(Wt + (size_t)(col + nf * 16) * 128 + ks * 32 + kg * 8);
    }

    __syncthreads();

    f32x4 acc[4][4];   // [m][nf]
    #pragma unroll
    for (int m = 0; m < 4; ++m)
        #pragma unroll
        for (int nf = 0; nf < 4; ++nf)
            acc[m][nf] = (f32x4){0.f, 0.f, 0.f, 0.f};

    #pragma unroll
    for (int ks = 0; ks < 4; ++ks) {
        bf16x8 Af[4];
        #pragma unroll
        for (int m = 0; m < 4; ++m) {
            int row = m * 16 + row_in;
            unsigned off = (unsigned)row * 256u +
                           (((unsigned)(ks * 64 + kg * 16)) ^ (((unsigned)row & 7u) << 4));
            Af[m] = *(const bf16x8*)((const char*)xs + off);
        }
        #pragma unroll
        for (int m = 0; m < 4; ++m)
            #pragma unroll
            for (int nf = 0; nf < 4; ++nf)
                acc[m][nf] = __builtin_amdgcn_mfma_f32_16x16x32_bf16(Af[m], Bf[nf][ks], acc[m][nf], 0, 0, 0);
    }

    // ---- epilogue: C/D layout col=lane&15, row=(lane>>4)*4+r ----
    int r0 = kg * 4;
    if (wv < 2) {       // cols 0..127 -> z (bf16)
        #pragma unroll
        for (int m = 0; m < 4; ++m)
            #pragma unroll
            for (int nf = 0; nf < 4; ++nf) {
                int col = wv * 64 + nf * 16 + row_in;
                #pragma unroll
                for (int r = 0; r < 4; ++r) {
                    int row = m0 + m * 16 + r0 + r;
                    if (row < N_NODES) z[(size_t)row * 128 + col] = f2bf(acc[m][nf][r]);
                }
            }
    } else {            // cols 128..255 -> out (f32) + b
        #pragma unroll
        for (int m = 0; m < 4; ++m)
            #pragma unroll
            for (int nf = 0; nf < 4; ++nf) {
                int col = (wv - 2) * 64 + nf * 16 + row_in;
                float bb = b[col];
                #pragma unroll
                for (int r = 0; r < 4; ++r) {
                    int row = m0 + m * 16 + r0 + r;
                    if (row < N_NODES) out[(size_t)row * 128 + col] = acc[m][nf][r] + bb;
                }
            }
    }
}

// ---------------- K4: wave-per-node aggregation, 4x unrolled for MLP ----------------
__global__ __launch_bounds__(256) void k_agg(const unsigned* __restrict__ row_ptr,
                                             const uint2* __restrict__ edata,
                                             const unsigned* __restrict__ zw,
                                             float* __restrict__ out) {
    int node = blockIdx.x * 4 + (threadIdx.x >> 6);
    int lane = threadIdx.x & 63;
    unsigned beg = row_ptr[node], end = row_ptr[node + 1];
    float a0 = 0.f, a1 = 0.f;
    unsigned j = beg;
    unsigned n4 = beg + ((end - beg) & ~3u);
    for (; j < n4; j += 4) {
        uint2 e0 = edata[j], e1 = edata[j + 1], e2 = edata[j + 2], e3 = edata[j + 3];
        unsigned z0 = zw[(size_t)e0.x * 64 + lane];
        unsigned z1 = zw[(size_t)e1.x * 64 + lane];
        unsigned z2 = zw[(size_t)e2.x * 64 + lane];
        unsigned z3 = zw[(size_t)e3.x * 64 + lane];
        float w0 = __uint_as_float(e0.y), w1 = __uint_as_float(e1.y);
        float w2 = __uint_as_float(e2.y), w3 = __uint_as_float(e3.y);
        a0 += w0 * __uint_as_float(z0 << 16);  a1 += w0 * __uint_as_float(z0 & 0xffff0000u);
        a0 += w1 * __uint_as_float(z1 << 16);  a1 += w1 * __uint_as_float(z1 & 0xffff0000u);
        a0 += w2 * __uint_as_float(z2 << 16);  a1 += w2 * __uint_as_float(z2 & 0xffff0000u);
        a0 += w3 * __uint_as_float(z3 << 16);  a1 += w3 * __uint_as_float(z3 & 0xffff0000u);
    }
    for (; j < end; ++j) {
        uint2 ed = edata[j];
        unsigned zz = zw[(size_t)ed.x * 64 + lane];
        float w = __uint_as_float(ed.y);
        a0 += w * __uint_as_float(zz << 16);
        a1 += w * __uint_as_float(zz & 0xffff0000u);
    }
    size_t o = (size_t)node * 128 + lane * 2;
    float2 v = *(const float2*)(out + o);
    *(float2*)(out + o) = make_float2(a0 + v.x, a1 + v.y);
}

// ---------------- K6: column sums / sumsq ----------------
__global__ __launch_bounds__(256) void k_stats(const float* __restrict__ out, float* stats) {
    int c = threadIdx.x & 127;
    int rbase = blockIdx.x * 2 + (threadIdx.x >> 7);
    float s = 0.f, q = 0.f;
    for (int r = rbase; r < N_NODES; r += gridDim.x * 2) {
        float v = out[(size_t)r * 128 + c];
        s += v; q += v * v;
    }
    __shared__ float lds[256];
    lds[threadIdx.x] = s;
    __syncthreads();
    if (threadIdx.x < 128) atomicAdd(&stats[c], lds[threadIdx.x] + lds[threadIdx.x + 128]);
    __syncthreads();
    lds[threadIdx.x] = q;
    __syncthreads();
    if (threadIdx.x < 128) atomicAdd(&stats[128 + c], lds[threadIdx.x] + lds[threadIdx.x + 128]);
}

// ---------------- K7: BN scale/shift ----------------
__global__ __launch_bounds__(128) void k_finalize(const float* __restrict__ stats,
                                                  const float* __restrict__ gamma,
                                                  const float* __restrict__ beta, float* ss) {
    int c = threadIdx.x;
    float mean = stats[c] * (1.f / N_NODES);
    float var  = stats[128 + c] * (1.f / N_NODES) - mean * mean;
    float sc = gamma[c] / sqrtf(var + 1e-5f);
    ss[c] = sc;
    ss[128 + c] = beta[c] - mean * sc;
}

// ---------------- K8: apply BN + ReLU (in place, float4) ----------------
__global__ __launch_bounds__(256) void k_apply(float* __restrict__ out, const float* __restrict__ ss) {
    __shared__ float s_sc[128], s_sh[128];
    if (threadIdx.x < 128) { s_sc[threadIdx.x] = ss[threadIdx.x]; s_sh[threadIdx.x] = ss[128 + threadIdx.x]; }
    __syncthreads();
    int idx = blockIdx.x * 256 + threadIdx.x;
    int total = N_NODES * 128 / 4;
    int stride = gridDim.x * 256;
    for (int i = idx; i < total; i += stride) {
        float4 v = ((const float4*)out)[i];
        int c = (i * 4) & 127;
        v.x = fmaxf(0.f, v.x * s_sc[c]     + s_sh[c]);
        v.y = fmaxf(0.f, v.y * s_sc[c + 1] + s_sh[c + 1]);
        v.z = fmaxf(0.f, v.z * s_sc[c + 2] + s_sh[c + 2]);
        v.w = fmaxf(0.f, v.w * s_sc[c + 3] + s_sh[c + 3]);
        ((float4*)out)[i] = v;
    }
}

extern "C" void kernel_launch(void* const* d_in, const int* in_sizes, int n_in,
                              void* d_out, int out_size, void* d_ws, size_t ws_size,
                              hipStream_t stream) {
    (void)in_sizes; (void)n_in; (void)out_size; (void)ws_size;
    const float* x      = (const float*)d_in[0];
    const float* edge_w = (const float*)d_in[1];
    const float* W      = (const float*)d_in[2];
    const float* b      = (const float*)d_in[3];
    const float* gamma  = (const float*)d_in[4];
    const float* beta   = (const float*)d_in[5];
    const int*   erow   = (const int*)d_in[6];
    const int*   ecol   = (const int*)d_in[7];
    float* out = (float*)d_out;

    uint8_t* ws = (uint8_t*)d_ws;
    unsigned* row_ptr = (unsigned*)(ws + 0);                     // (N+1)*4
    unsigned* cursor  = (unsigned*)(ws + 400128);                // N*4  (dead after k_fill)
    unsigned short* Wt = (unsigned short*)(ws + 400128);         // 64KB, reuses cursor space
    uint2*    edata   = (uint2*)(ws + 800256);                   // E*8
    unsigned short* z = (unsigned short*)(ws + 13600256);        // N*128*2
    float*    stats   = (float*)(ws + 39200256);                 // 256 f
    float*    ss      = (float*)(ws + 39201280);                 // 256 f
    unsigned* bsums   = (unsigned*)(ws + 39202304);              // 196*4

    const int NB_SCAN = (N_NODES + 511) / 512;   // 196

    hipLaunchKernelGGL(k_zero, dim3((N_NODES + 255) / 256), dim3(256), 0, stream, cursor, stats);
    hipLaunchKernelGGL(k_hist, dim3(2048), dim3(256), 0, stream, erow, cursor);
    hipLaunchKernelGGL(k_scan_bsum, dim3(NB_SCAN), dim3(512), 0, stream, cursor, bsums);
    hipLaunchKernelGGL(k_scan_top, dim3(1), dim3(256), 0, stream, bsums, NB_SCAN);
    hipLaunchKernelGGL(k_scan_apply, dim3(NB_SCAN), dim3(512), 0, stream, cursor, bsums, row_ptr, cursor);
    hipLaunchKernelGGL(k_fill, dim3(2048), dim3(256), 0, stream, erow, ecol, edge_w, cursor, edata);
    hipLaunchKernelGGL(k_prep, dim3(128), dim3(256), 0, stream, W, Wt);
    hipLaunchKernelGGL(k_gemm, dim3((N_NODES + 63) / 64), dim3(256), 0, stream, x, Wt, b, z, out);
    hipLaunchKernelGGL(k_agg, dim3(N_NODES / 4), dim3(256), 0, stream, row_ptr, edata,
                       (const unsigned*)z, out);
    hipLaunchKernelGGL(k_stats, dim3(1024), dim3(256), 0, stream, out, stats);
    hipLaunchKernelGGL(k_finalize, dim3(1), dim3(128), 0, stream, stats, gamma, beta, ss);
    hipLaunchKernelGGL(k_apply, dim3(2048), dim3(256), 0, stream, out, ss);
}

// Round 3
// 329.610 us; speedup vs baseline: 1.6125x; 1.1749x over previous
//
#include <hip/hip_runtime.h>
#include <hip/hip_bf16.h>
#include <stdint.h>

#define N_NODES 100000
#define N_EDGES 1600000
#define D 128

typedef __attribute__((ext_vector_type(8))) __bf16 bf16x8;
typedef __attribute__((ext_vector_type(4))) float f32x4;

__device__ __forceinline__ unsigned short f2bf(float f) {
    unsigned u = __float_as_uint(f);
    unsigned r = (u + 0x7fffu + ((u >> 16) & 1u)) >> 16;   // RNE
    return (unsigned short)r;
}
__device__ __forceinline__ unsigned pack2bf(float a, float b) {
    return (unsigned)f2bf(a) | ((unsigned)f2bf(b) << 16);
}

// ---------------- K0: zero cursor (counts) + stats ----------------
__global__ __launch_bounds__(256) void k_zero(unsigned* cursor, float* stats) {
    int i = blockIdx.x * 256 + threadIdx.x;
    if (i < N_NODES) cursor[i] = 0u;
    if (blockIdx.x == 0) stats[threadIdx.x] = 0.f;   // 256 floats: sum, sumsq
}

// ---------------- K1: histogram of edge_row ----------------
__global__ __launch_bounds__(256) void k_hist(const int* __restrict__ row, unsigned* cursor) {
    int i = blockIdx.x * 256 + threadIdx.x;
    int stride = gridDim.x * 256;
    for (int e = i; e < N_EDGES; e += stride)
        atomicAdd(&cursor[row[e]], 1u);
}

// ---------------- K2a: per-block sums for scan ----------------
__global__ __launch_bounds__(512) void k_scan_bsum(const unsigned* __restrict__ counts, unsigned* bsums) {
    __shared__ unsigned lds[512];
    int t = threadIdx.x;
    int g = blockIdx.x * 512 + t;
    lds[t] = (g < N_NODES) ? counts[g] : 0u;
    __syncthreads();
    for (int off = 256; off > 0; off >>= 1) {
        if (t < off) lds[t] += lds[t + off];
        __syncthreads();
    }
    if (t == 0) bsums[blockIdx.x] = lds[0];
}

// ---------------- K2b: exclusive scan of block sums (1 block) ----------------
__global__ __launch_bounds__(256) void k_scan_top(unsigned* bsums, int nb) {
    __shared__ unsigned lds[256];
    int t = threadIdx.x;
    lds[t] = (t < nb) ? bsums[t] : 0u;
    __syncthreads();
    for (int off = 1; off < 256; off <<= 1) {
        unsigned add = (t >= off) ? lds[t - off] : 0u;
        __syncthreads();
        lds[t] += add;
        __syncthreads();
    }
    if (t < nb) bsums[t] = (t == 0) ? 0u : lds[t - 1];
}

// ---------------- K2c: per-chunk exclusive scan + offset -> row_ptr, cursor ----------------
__global__ __launch_bounds__(512) void k_scan_apply(const unsigned* __restrict__ counts,
                                                    const unsigned* __restrict__ bsums,
                                                    unsigned* row_ptr, unsigned* cursor) {
    __shared__ unsigned lds[512];
    int t = threadIdx.x;
    int g = blockIdx.x * 512 + t;
    unsigned v = (g < N_NODES) ? counts[g] : 0u;
    lds[t] = v;
    __syncthreads();
    for (int off = 1; off < 512; off <<= 1) {
        unsigned add = (t >= off) ? lds[t - off] : 0u;
        __syncthreads();
        lds[t] += add;
        __syncthreads();
    }
    unsigned excl = ((t == 0) ? 0u : lds[t - 1]) + bsums[blockIdx.x];
    if (g < N_NODES) { row_ptr[g] = excl; cursor[g] = excl; }
    if (g == 0) row_ptr[N_NODES] = N_EDGES;
}

// ---------------- K3: class-partitioned fill ----------------
// class = row/12500 (8 contiguous row ranges); block handles only its class so each
// class's edata/cursor slice is written from (empirically) one XCD -> full-line L2
// residency -> writeback 12.8MB instead of 64B/edge = 102MB.
#define FILL_CHUNK 16000
__global__ __launch_bounds__(256) void k_fill(const int* __restrict__ row, const int* __restrict__ col,
                                              const float* __restrict__ w, unsigned* cursor,
                                              uint2* __restrict__ edata) {
    unsigned cls = blockIdx.x & 7;
    int base = (blockIdx.x >> 3) * FILL_CHUNK;
    int end = base + FILL_CHUNK;
    if (end > N_EDGES) end = N_EDGES;
    for (int e = base + threadIdx.x; e < end; e += 256) {
        int r = row[e];
        if ((unsigned)r / 12500u == cls) {
            unsigned pos = atomicAdd(&cursor[r], 1u);
            edata[pos] = make_uint2((unsigned)col[e], __float_as_uint(w[e]));
        }
    }
}

// ---------------- Kp: W -> Wt bf16 [n=256][k=128]  (runs after k_fill, reuses cursor space) ----
__global__ __launch_bounds__(256) void k_prep(const float* __restrict__ W, unsigned short* __restrict__ Wt) {
    int i = blockIdx.x * 256 + threadIdx.x;   // 32768
    int n = i >> 7, k = i & 127;
    float v = (n < 128) ? W[(size_t)k * 128 + n] : W[(size_t)(128 + k) * 128 + (n - 128)];
    Wt[i] = f2bf(v);
}

// ---------------- K5: MFMA GEMM  z = bf16(x@W_top), out = x@W_bot + b ----------------
// block: 64 rows x 256 cols, K=128. 4 waves; wave w -> cols [w*64, w*64+64).
__global__ __launch_bounds__(256) void k_gemm(const float* __restrict__ x,
                                              const unsigned short* __restrict__ Wt,
                                              const float* __restrict__ b,
                                              unsigned short* __restrict__ z,
                                              float* __restrict__ out) {
    __shared__ unsigned short xs[64 * 128];   // bf16, XOR-swizzled, 16KB
    int tid = threadIdx.x;
    int lane = tid & 63;
    int wv = tid >> 6;
    int m0 = blockIdx.x * 64;
    int row_in = lane & 15;
    int kg = lane >> 4;        // 0..3

    // ---- stage x tile as bf16 into LDS (swizzled: byte ^= (row&7)<<4) ----
    #pragma unroll
    for (int q = 0; q < 4; ++q) {
        int c = q * 256 + tid;          // 1024 chunks of 8 bf16
        int row = c >> 4;
        int kc = (c & 15) * 8;
        float4 v0, v1;
        int gr = m0 + row;
        if (gr < N_NODES) {
            v0 = *(const float4*)(x + (size_t)gr * 128 + kc);
            v1 = *(const float4*)(x + (size_t)gr * 128 + kc + 4);
        } else {
            v0 = make_float4(0.f, 0.f, 0.f, 0.f);
            v1 = v0;
        }
        uint4 p;
        p.x = pack2bf(v0.x, v0.y); p.y = pack2bf(v0.z, v0.w);
        p.z = pack2bf(v1.x, v1.y); p.w = pack2bf(v1.z, v1.w);
        unsigned off = (unsigned)row * 256u + (((unsigned)kc * 2u) ^ (((unsigned)row & 7u) << 4));
        *(uint4*)((char*)xs + off) = p;
    }

    // ---- B fragments -> registers (from Wt, L2-resident) ----
    bf16x8 Bf[4][4];   // [nf][ks]
    {
        int col = wv * 64 + row_in;
        #pragma unroll
        for (int nf = 0; nf < 4; ++nf)
            #pragma unroll
            for (int ks = 0; ks < 4; ++ks)
                Bf[nf][ks] = *(const bf16x8*)(Wt + (size_t)(col + nf * 16) * 128 + ks * 32 + kg * 8);
    }

    __syncthreads();

    f32x4 acc[4][4];   // [m][nf]
    #pragma unroll
    for (int m = 0; m < 4; ++m)
        #pragma unroll
        for (int nf = 0; nf < 4; ++nf)
            acc[m][nf] = (f32x4){0.f, 0.f, 0.f, 0.f};

    #pragma unroll
    for (int ks = 0; ks < 4; ++ks) {
        bf16x8 Af[4];
        #pragma unroll
        for (int m = 0; m < 4; ++m) {
            int row = m * 16 + row_in;
            unsigned off = (unsigned)row * 256u +
                           (((unsigned)(ks * 64 + kg * 16)) ^ (((unsigned)row & 7u) << 4));
            Af[m] = *(const bf16x8*)((const char*)xs + off);
        }
        #pragma unroll
        for (int m = 0; m < 4; ++m)
            #pragma unroll
            for (int nf = 0; nf < 4; ++nf)
                acc[m][nf] = __builtin_amdgcn_mfma_f32_16x16x32_bf16(Af[m], Bf[nf][ks], acc[m][nf], 0, 0, 0);
    }

    // ---- epilogue: C/D layout col=lane&15, row=(lane>>4)*4+r ----
    int r0 = kg * 4;
    if (wv < 2) {       // cols 0..127 -> z (bf16)
        #pragma unroll
        for (int m = 0; m < 4; ++m)
            #pragma unroll
            for (int nf = 0; nf < 4; ++nf) {
                int col = wv * 64 + nf * 16 + row_in;
                #pragma unroll
                for (int r = 0; r < 4; ++r) {
                    int row = m0 + m * 16 + r0 + r;
                    if (row < N_NODES) z[(size_t)row * 128 + col] = f2bf(acc[m][nf][r]);
                }
            }
    } else {            // cols 128..255 -> out (f32) + b
        #pragma unroll
        for (int m = 0; m < 4; ++m)
            #pragma unroll
            for (int nf = 0; nf < 4; ++nf) {
                int col = (wv - 2) * 64 + nf * 16 + row_in;
                float bb = b[col];
                #pragma unroll
                for (int r = 0; r < 4; ++r) {
                    int row = m0 + m * 16 + r0 + r;
                    if (row < N_NODES) out[(size_t)row * 128 + col] = acc[m][nf][r] + bb;
                }
            }
    }
}

// ---------------- K4: wave-per-node aggregation, 4x unrolled for MLP ----------------
__global__ __launch_bounds__(256) void k_agg(const unsigned* __restrict__ row_ptr,
                                             const uint2* __restrict__ edata,
                                             const unsigned* __restrict__ zw,
                                             float* __restrict__ out) {
    int node = blockIdx.x * 4 + (threadIdx.x >> 6);
    int lane = threadIdx.x & 63;
    unsigned beg = row_ptr[node], end = row_ptr[node + 1];
    float a0 = 0.f, a1 = 0.f;
    unsigned j = beg;
    unsigned n4 = beg + ((end - beg) & ~3u);
    for (; j < n4; j += 4) {
        uint2 e0 = edata[j], e1 = edata[j + 1], e2 = edata[j + 2], e3 = edata[j + 3];
        unsigned z0 = zw[(size_t)e0.x * 64 + lane];
        unsigned z1 = zw[(size_t)e1.x * 64 + lane];
        unsigned z2 = zw[(size_t)e2.x * 64 + lane];
        unsigned z3 = zw[(size_t)e3.x * 64 + lane];
        float w0 = __uint_as_float(e0.y), w1 = __uint_as_float(e1.y);
        float w2 = __uint_as_float(e2.y), w3 = __uint_as_float(e3.y);
        a0 += w0 * __uint_as_float(z0 << 16);  a1 += w0 * __uint_as_float(z0 & 0xffff0000u);
        a0 += w1 * __uint_as_float(z1 << 16);  a1 += w1 * __uint_as_float(z1 & 0xffff0000u);
        a0 += w2 * __uint_as_float(z2 << 16);  a1 += w2 * __uint_as_float(z2 & 0xffff0000u);
        a0 += w3 * __uint_as_float(z3 << 16);  a1 += w3 * __uint_as_float(z3 & 0xffff0000u);
    }
    for (; j < end; ++j) {
        uint2 ed = edata[j];
        unsigned zz = zw[(size_t)ed.x * 64 + lane];
        float w = __uint_as_float(ed.y);
        a0 += w * __uint_as_float(zz << 16);
        a1 += w * __uint_as_float(zz & 0xffff0000u);
    }
    size_t o = (size_t)node * 128 + lane * 2;
    float2 v = *(const float2*)(out + o);
    *(float2*)(out + o) = make_float2(a0 + v.x, a1 + v.y);
}

// ---------------- K6: column sums / sumsq ----------------
__global__ __launch_bounds__(256) void k_stats(const float* __restrict__ out, float* stats) {
    int c = threadIdx.x & 127;
    int rbase = blockIdx.x * 2 + (threadIdx.x >> 7);
    float s = 0.f, q = 0.f;
    for (int r = rbase; r < N_NODES; r += gridDim.x * 2) {
        float v = out[(size_t)r * 128 + c];
        s += v; q += v * v;
    }
    __shared__ float lds[256];
    lds[threadIdx.x] = s;
    __syncthreads();
    if (threadIdx.x < 128) atomicAdd(&stats[c], lds[threadIdx.x] + lds[threadIdx.x + 128]);
    __syncthreads();
    lds[threadIdx.x] = q;
    __syncthreads();
    if (threadIdx.x < 128) atomicAdd(&stats[128 + c], lds[threadIdx.x] + lds[threadIdx.x + 128]);
}

// ---------------- K7: BN scale/shift ----------------
__global__ __launch_bounds__(128) void k_finalize(const float* __restrict__ stats,
                                                  const float* __restrict__ gamma,
                                                  const float* __restrict__ beta, float* ss) {
    int c = threadIdx.x;
    float mean = stats[c] * (1.f / N_NODES);
    float var  = stats[128 + c] * (1.f / N_NODES) - mean * mean;
    float sc = gamma[c] / sqrtf(var + 1e-5f);
    ss[c] = sc;
    ss[128 + c] = beta[c] - mean * sc;
}

// ---------------- K8: apply BN + ReLU (in place, float4) ----------------
__global__ __launch_bounds__(256) void k_apply(float* __restrict__ out, const float* __restrict__ ss) {
    __shared__ float s_sc[128], s_sh[128];
    if (threadIdx.x < 128) { s_sc[threadIdx.x] = ss[threadIdx.x]; s_sh[threadIdx.x] = ss[128 + threadIdx.x]; }
    __syncthreads();
    int idx = blockIdx.x * 256 + threadIdx.x;
    int total = N_NODES * 128 / 4;
    int stride = gridDim.x * 256;
    for (int i = idx; i < total; i += stride) {
        float4 v = ((const float4*)out)[i];
        int c = (i * 4) & 127;
        v.x = fmaxf(0.f, v.x * s_sc[c]     + s_sh[c]);
        v.y = fmaxf(0.f, v.y * s_sc[c + 1] + s_sh[c + 1]);
        v.z = fmaxf(0.f, v.z * s_sc[c + 2] + s_sh[c + 2]);
        v.w = fmaxf(0.f, v.w * s_sc[c + 3] + s_sh[c + 3]);
        ((float4*)out)[i] = v;
    }
}

extern "C" void kernel_launch(void* const* d_in, const int* in_sizes, int n_in,
                              void* d_out, int out_size, void* d_ws, size_t ws_size,
                              hipStream_t stream) {
    (void)in_sizes; (void)n_in; (void)out_size; (void)ws_size;
    const float* x      = (const float*)d_in[0];
    const float* edge_w = (const float*)d_in[1];
    const float* W      = (const float*)d_in[2];
    const float* b      = (const float*)d_in[3];
    const float* gamma  = (const float*)d_in[4];
    const float* beta   = (const float*)d_in[5];
    const int*   erow   = (const int*)d_in[6];
    const int*   ecol   = (const int*)d_in[7];
    float* out = (float*)d_out;

    uint8_t* ws = (uint8_t*)d_ws;
    unsigned* row_ptr = (unsigned*)(ws + 0);                     // (N+1)*4
    unsigned* cursor  = (unsigned*)(ws + 400128);                // N*4  (dead after k_fill)
    unsigned short* Wt = (unsigned short*)(ws + 400128);         // 64KB, reuses cursor space
    uint2*    edata   = (uint2*)(ws + 800256);                   // E*8
    unsigned short* z = (unsigned short*)(ws + 13600256);        // N*128*2
    float*    stats   = (float*)(ws + 39200256);                 // 256 f
    float*    ss      = (float*)(ws + 39201280);                 // 256 f
    unsigned* bsums   = (unsigned*)(ws + 39202304);              // 196*4

    const int NB_SCAN = (N_NODES + 511) / 512;   // 196
    const int NCHUNK = (N_EDGES + FILL_CHUNK - 1) / FILL_CHUNK;  // 100

    hipLaunchKernelGGL(k_zero, dim3((N_NODES + 255) / 256), dim3(256), 0, stream, cursor, stats);
    hipLaunchKernelGGL(k_hist, dim3(2048), dim3(256), 0, stream, erow, cursor);
    hipLaunchKernelGGL(k_scan_bsum, dim3(NB_SCAN), dim3(512), 0, stream, cursor, bsums);
    hipLaunchKernelGGL(k_scan_top, dim3(1), dim3(256), 0, stream, bsums, NB_SCAN);
    hipLaunchKernelGGL(k_scan_apply, dim3(NB_SCAN), dim3(512), 0, stream, cursor, bsums, row_ptr, cursor);
    hipLaunchKernelGGL(k_fill, dim3(NCHUNK * 8), dim3(256), 0, stream, erow, ecol, edge_w, cursor, edata);
    hipLaunchKernelGGL(k_prep, dim3(128), dim3(256), 0, stream, W, Wt);
    hipLaunchKernelGGL(k_gemm, dim3((N_NODES + 63) / 64), dim3(256), 0, stream, x, Wt, b, z, out);
    hipLaunchKernelGGL(k_agg, dim3(N_NODES / 4), dim3(256), 0, stream, row_ptr, edata,
                       (const unsigned*)z, out);
    hipLaunchKernelGGL(k_stats, dim3(1024), dim3(256), 0, stream, out, stats);
    hipLaunchKernelGGL(k_finalize, dim3(1), dim3(128), 0, stream, stats, gamma, beta, ss);
    hipLaunchKernelGGL(k_apply, dim3(2048), dim3(256), 0, stream, out, ss);
}

// Round 4
// 328.682 us; speedup vs baseline: 1.6171x; 1.0028x over previous
//
#include <hip/hip_runtime.h>
#include <hip/hip_bf16.h>
#include <stdint.h>

#define N_NODES 100000
#define N_EDGES 1600000
#define D 128

#define NBKT 391            // ceil(100000/256) buckets of 256 nodes
#define FILL_CHUNK 16000
#define NCHUNK 100
#define BCAP 6144           // LDS edge staging cap per bucket (mean 4096, sigma 64)

typedef __attribute__((ext_vector_type(8))) __bf16 bf16x8;
typedef __attribute__((ext_vector_type(4))) float f32x4;

__device__ __forceinline__ unsigned short f2bf(float f) {
    unsigned u = __float_as_uint(f);
    unsigned r = (u + 0x7fffu + ((u >> 16) & 1u)) >> 16;   // RNE
    return (unsigned short)r;
}
__device__ __forceinline__ unsigned pack2bf(float a, float b) {
    return (unsigned)f2bf(a) | ((unsigned)f2bf(b) << 16);
}

// ---------------- K0: zero counts + stats ----------------
__global__ __launch_bounds__(256) void k_zero(unsigned* cursor, float* stats) {
    int i = blockIdx.x * 256 + threadIdx.x;
    if (i < N_NODES) cursor[i] = 0u;
    if (blockIdx.x == 0) stats[threadIdx.x] = 0.f;   // 256 floats: sum, sumsq
}

// ---------------- K1: histogram of edge_row ----------------
__global__ __launch_bounds__(256) void k_hist(const int* __restrict__ row, unsigned* cursor) {
    int i = blockIdx.x * 256 + threadIdx.x;
    int stride = gridDim.x * 256;
    for (int e = i; e < N_EDGES; e += stride)
        atomicAdd(&cursor[row[e]], 1u);
}

// ---------------- K2a: per-block sums for scan ----------------
__global__ __launch_bounds__(512) void k_scan_bsum(const unsigned* __restrict__ counts, unsigned* bsums) {
    __shared__ unsigned lds[512];
    int t = threadIdx.x;
    int g = blockIdx.x * 512 + t;
    lds[t] = (g < N_NODES) ? counts[g] : 0u;
    __syncthreads();
    for (int off = 256; off > 0; off >>= 1) {
        if (t < off) lds[t] += lds[t + off];
        __syncthreads();
    }
    if (t == 0) bsums[blockIdx.x] = lds[0];
}

// ---------------- K2b: exclusive scan of block sums (1 block) ----------------
__global__ __launch_bounds__(256) void k_scan_top(unsigned* bsums, int nb) {
    __shared__ unsigned lds[256];
    int t = threadIdx.x;
    lds[t] = (t < nb) ? bsums[t] : 0u;
    __syncthreads();
    for (int off = 1; off < 256; off <<= 1) {
        unsigned add = (t >= off) ? lds[t - off] : 0u;
        __syncthreads();
        lds[t] += add;
        __syncthreads();
    }
    if (t < nb) bsums[t] = (t == 0) ? 0u : lds[t - 1];
}

// ---------------- K2c: per-chunk exclusive scan + offset -> row_ptr ----------------
__global__ __launch_bounds__(512) void k_scan_apply(const unsigned* __restrict__ counts,
                                                    const unsigned* __restrict__ bsums,
                                                    unsigned* row_ptr) {
    __shared__ unsigned lds[512];
    int t = threadIdx.x;
    int g = blockIdx.x * 512 + t;
    unsigned v = (g < N_NODES) ? counts[g] : 0u;
    lds[t] = v;
    __syncthreads();
    for (int off = 1; off < 512; off <<= 1) {
        unsigned add = (t >= off) ? lds[t - off] : 0u;
        __syncthreads();
        lds[t] += add;
        __syncthreads();
    }
    unsigned excl = ((t == 0) ? 0u : lds[t - 1]) + bsums[blockIdx.x];
    if (g < N_NODES) row_ptr[g] = excl;
    if (g == 0) row_ptr[N_NODES] = N_EDGES;
}

// ---------------- Kp: W -> Wt bf16 [n=256][k=128]; also init gbcur from row_ptr ----------------
__global__ __launch_bounds__(256) void k_prep(const float* __restrict__ W, unsigned short* __restrict__ Wt,
                                              const unsigned* __restrict__ row_ptr, unsigned* gbcur) {
    int i = blockIdx.x * 256 + threadIdx.x;   // 32768
    if (i < NBKT) gbcur[i] = row_ptr[i << 8];
    int n = i >> 7, k = i & 127;
    float v = (n < 128) ? W[(size_t)k * 128 + n] : W[(size_t)(128 + k) * 128 + (n - 128)];
    Wt[i] = f2bf(v);
}

// ---------------- K3a: bin edges by 256-node bucket, ranges at final CSR bases ----------------
// Per bucket, this block's writes form a private contiguous run written in a tight
// window -> L2 write-merge -> full-line flushes (vs 64B/edge scattered before).
__global__ __launch_bounds__(256) void k_binA(const int* __restrict__ row, const int* __restrict__ col,
                                              const float* __restrict__ w,
                                              unsigned* gbcur, uint2* __restrict__ edata) {
    __shared__ unsigned lcur[NBKT];
    int tid = threadIdx.x;
    int base = blockIdx.x * FILL_CHUNK;
    int end = base + FILL_CHUNK > N_EDGES ? N_EDGES : base + FILL_CHUNK;
    for (int i = tid; i < NBKT; i += 256) lcur[i] = 0u;
    __syncthreads();
    for (int e = base + tid; e < end; e += 256)
        atomicAdd(&lcur[(unsigned)row[e] >> 8], 1u);
    __syncthreads();
    for (int i = tid; i < NBKT; i += 256) {
        unsigned c = lcur[i];
        lcur[i] = c ? atomicAdd(&gbcur[i], c) : 0u;   // reserve contiguous run
    }
    __syncthreads();
    for (int e = base + tid; e < end; e += 256) {
        unsigned r = (unsigned)row[e];
        unsigned c = (unsigned)__builtin_nontemporal_load(col + e);
        float    ww = __builtin_nontemporal_load(w + e);
        unsigned enc = c | ((r & 255u) << 17);
        unsigned pos = atomicAdd(&lcur[r >> 8], 1u);
        edata[pos] = make_uint2(enc, __float_as_uint(ww));
    }
}

// ---------------- K3b: refine bucket to exact per-node CSR, in place via LDS ----------------
__global__ __launch_bounds__(256) void k_binB(const unsigned* __restrict__ row_ptr,
                                              uint2* __restrict__ edata) {
    __shared__ uint2 st[BCAP];
    __shared__ unsigned cur[256];
    int b = blockIdx.x, tid = threadIdx.x;
    unsigned gb0 = row_ptr[b << 8];
    int hi = (b + 1) << 8; if (hi > N_NODES) hi = N_NODES;
    unsigned gb1 = row_ptr[hi];
    int cnt = (int)(gb1 - gb0);
    int node = (b << 8) + tid;
    cur[tid] = (node < N_NODES) ? row_ptr[node] : 0u;
    int ns = cnt < BCAP ? cnt : BCAP;
    for (int i = tid; i < ns; i += 256) st[i] = edata[gb0 + i];
    uint2 ov[4]; int nov = 0;
    for (int i = BCAP + tid; i < cnt; i += 256)    // statistically dead overflow guard
        if (nov < 4) ov[nov++] = edata[gb0 + i];
    __syncthreads();
    for (int i = tid; i < ns; i += 256) {
        uint2 e = st[i];
        unsigned pos = atomicAdd(&cur[e.x >> 17], 1u);
        edata[pos] = make_uint2(e.x & 0x1FFFFu, e.y);
    }
    for (int j = 0; j < nov; ++j) {
        uint2 e = ov[j];
        unsigned pos = atomicAdd(&cur[e.x >> 17], 1u);
        edata[pos] = make_uint2(e.x & 0x1FFFFu, e.y);
    }
}

// ---------------- K5: MFMA GEMM  z = bf16(x@W_top), out = x@W_bot + b ----------------
__global__ __launch_bounds__(256) void k_gemm(const float* __restrict__ x,
                                              const unsigned short* __restrict__ Wt,
                                              const float* __restrict__ b,
                                              unsigned short* __restrict__ z,
                                              float* __restrict__ out) {
    __shared__ unsigned short xs[64 * 128];   // bf16, XOR-swizzled, 16KB
    int tid = threadIdx.x;
    int lane = tid & 63;
    int wv = tid >> 6;
    int m0 = blockIdx.x * 64;
    int row_in = lane & 15;
    int kg = lane >> 4;        // 0..3

    #pragma unroll
    for (int q = 0; q < 4; ++q) {
        int c = q * 256 + tid;          // 1024 chunks of 8 bf16
        int row = c >> 4;
        int kc = (c & 15) * 8;
        float4 v0, v1;
        int gr = m0 + row;
        if (gr < N_NODES) {
            v0 = *(const float4*)(x + (size_t)gr * 128 + kc);
            v1 = *(const float4*)(x + (size_t)gr * 128 + kc + 4);
        } else {
            v0 = make_float4(0.f, 0.f, 0.f, 0.f);
            v1 = v0;
        }
        uint4 p;
        p.x = pack2bf(v0.x, v0.y); p.y = pack2bf(v0.z, v0.w);
        p.z = pack2bf(v1.x, v1.y); p.w = pack2bf(v1.z, v1.w);
        unsigned off = (unsigned)row * 256u + (((unsigned)kc * 2u) ^ (((unsigned)row & 7u) << 4));
        *(uint4*)((char*)xs + off) = p;
    }

    bf16x8 Bf[4][4];   // [nf][ks]
    {
        int col = wv * 64 + row_in;
        #pragma unroll
        for (int nf = 0; nf < 4; ++nf)
            #pragma unroll
            for (int ks = 0; ks < 4; ++ks)
                Bf[nf][ks] = *(const bf16x8*)(Wt + (size_t)(col + nf * 16) * 128 + ks * 32 + kg * 8);
    }

    __syncthreads();

    f32x4 acc[4][4];   // [m][nf]
    #pragma unroll
    for (int m = 0; m < 4; ++m)
        #pragma unroll
        for (int nf = 0; nf < 4; ++nf)
            acc[m][nf] = (f32x4){0.f, 0.f, 0.f, 0.f};

    #pragma unroll
    for (int ks = 0; ks < 4; ++ks) {
        bf16x8 Af[4];
        #pragma unroll
        for (int m = 0; m < 4; ++m) {
            int row = m * 16 + row_in;
            unsigned off = (unsigned)row * 256u +
                           (((unsigned)(ks * 64 + kg * 16)) ^ (((unsigned)row & 7u) << 4));
            Af[m] = *(const bf16x8*)((const char*)xs + off);
        }
        #pragma unroll
        for (int m = 0; m < 4; ++m)
            #pragma unroll
            for (int nf = 0; nf < 4; ++nf)
                acc[m][nf] = __builtin_amdgcn_mfma_f32_16x16x32_bf16(Af[m], Bf[nf][ks], acc[m][nf], 0, 0, 0);
    }

    int r0 = kg * 4;
    if (wv < 2) {       // cols 0..127 -> z (bf16)
        #pragma unroll
        for (int m = 0; m < 4; ++m)
            #pragma unroll
            for (int nf = 0; nf < 4; ++nf) {
                int col = wv * 64 + nf * 16 + row_in;
                #pragma unroll
                for (int r = 0; r < 4; ++r) {
                    int row = m0 + m * 16 + r0 + r;
                    if (row < N_NODES) z[(size_t)row * 128 + col] = f2bf(acc[m][nf][r]);
                }
            }
    } else {            // cols 128..255 -> out (f32) + b
        #pragma unroll
        for (int m = 0; m < 4; ++m)
            #pragma unroll
            for (int nf = 0; nf < 4; ++nf) {
                int col = (wv - 2) * 64 + nf * 16 + row_in;
                float bb = b[col];
                #pragma unroll
                for (int r = 0; r < 4; ++r) {
                    int row = m0 + m * 16 + r0 + r;
                    if (row < N_NODES) out[(size_t)row * 128 + col] = acc[m][nf][r] + bb;
                }
            }
    }
}

// ---------------- K4: wave-per-node aggregation, 8x unrolled for MLP ----------------
__global__ __launch_bounds__(256) void k_agg(const unsigned* __restrict__ row_ptr,
                                             const uint2* __restrict__ edata,
                                             const unsigned* __restrict__ zw,
                                             float* __restrict__ out) {
    int node = blockIdx.x * 4 + (threadIdx.x >> 6);
    int lane = threadIdx.x & 63;
    unsigned beg = row_ptr[node], end = row_ptr[node + 1];
    float a0 = 0.f, a1 = 0.f;
    unsigned j = beg;
    unsigned n8 = beg + ((end - beg) & ~7u);
    for (; j < n8; j += 8) {
        uint2 e[8]; unsigned zz[8];
        #pragma unroll
        for (int q = 0; q < 8; ++q) e[q] = edata[j + q];
        #pragma unroll
        for (int q = 0; q < 8; ++q) zz[q] = zw[(size_t)e[q].x * 64 + lane];
        #pragma unroll
        for (int q = 0; q < 8; ++q) {
            float w = __uint_as_float(e[q].y);
            a0 += w * __uint_as_float(zz[q] << 16);
            a1 += w * __uint_as_float(zz[q] & 0xffff0000u);
        }
    }
    for (; j < end; ++j) {
        uint2 ed = edata[j];
        unsigned zz = zw[(size_t)ed.x * 64 + lane];
        float w = __uint_as_float(ed.y);
        a0 += w * __uint_as_float(zz << 16);
        a1 += w * __uint_as_float(zz & 0xffff0000u);
    }
    size_t o = (size_t)node * 128 + lane * 2;
    float2 v = *(const float2*)(out + o);
    *(float2*)(out + o) = make_float2(a0 + v.x, a1 + v.y);
}

// ---------------- K6: column sums / sumsq ----------------
__global__ __launch_bounds__(256) void k_stats(const float* __restrict__ out, float* stats) {
    int c = threadIdx.x & 127;
    int rbase = blockIdx.x * 2 + (threadIdx.x >> 7);
    float s = 0.f, q = 0.f;
    for (int r = rbase; r < N_NODES; r += gridDim.x * 2) {
        float v = out[(size_t)r * 128 + c];
        s += v; q += v * v;
    }
    __shared__ float lds[256];
    lds[threadIdx.x] = s;
    __syncthreads();
    if (threadIdx.x < 128) atomicAdd(&stats[c], lds[threadIdx.x] + lds[threadIdx.x + 128]);
    __syncthreads();
    lds[threadIdx.x] = q;
    __syncthreads();
    if (threadIdx.x < 128) atomicAdd(&stats[128 + c], lds[threadIdx.x] + lds[threadIdx.x + 128]);
}

// ---------------- K7: BN scale/shift ----------------
__global__ __launch_bounds__(128) void k_finalize(const float* __restrict__ stats,
                                                  const float* __restrict__ gamma,
                                                  const float* __restrict__ beta, float* ss) {
    int c = threadIdx.x;
    float mean = stats[c] * (1.f / N_NODES);
    float var  = stats[128 + c] * (1.f / N_NODES) - mean * mean;
    float sc = gamma[c] / sqrtf(var + 1e-5f);
    ss[c] = sc;
    ss[128 + c] = beta[c] - mean * sc;
}

// ---------------- K8: apply BN + ReLU (in place, float4) ----------------
__global__ __launch_bounds__(256) void k_apply(float* __restrict__ out, const float* __restrict__ ss) {
    __shared__ float s_sc[128], s_sh[128];
    if (threadIdx.x < 128) { s_sc[threadIdx.x] = ss[threadIdx.x]; s_sh[threadIdx.x] = ss[128 + threadIdx.x]; }
    __syncthreads();
    int idx = blockIdx.x * 256 + threadIdx.x;
    int total = N_NODES * 128 / 4;
    int stride = gridDim.x * 256;
    for (int i = idx; i < total; i += stride) {
        float4 v = ((const float4*)out)[i];
        int c = (i * 4) & 127;
        v.x = fmaxf(0.f, v.x * s_sc[c]     + s_sh[c]);
        v.y = fmaxf(0.f, v.y * s_sc[c + 1] + s_sh[c + 1]);
        v.z = fmaxf(0.f, v.z * s_sc[c + 2] + s_sh[c + 2]);
        v.w = fmaxf(0.f, v.w * s_sc[c + 3] + s_sh[c + 3]);
        ((float4*)out)[i] = v;
    }
}

extern "C" void kernel_launch(void* const* d_in, const int* in_sizes, int n_in,
                              void* d_out, int out_size, void* d_ws, size_t ws_size,
                              hipStream_t stream) {
    (void)in_sizes; (void)n_in; (void)out_size; (void)ws_size;
    const float* x      = (const float*)d_in[0];
    const float* edge_w = (const float*)d_in[1];
    const float* W      = (const float*)d_in[2];
    const float* b      = (const float*)d_in[3];
    const float* gamma  = (const float*)d_in[4];
    const float* beta   = (const float*)d_in[5];
    const int*   erow   = (const int*)d_in[6];
    const int*   ecol   = (const int*)d_in[7];
    float* out = (float*)d_out;

    uint8_t* ws = (uint8_t*)d_ws;
    unsigned* row_ptr = (unsigned*)(ws + 0);                     // (N+1)*4
    unsigned* counts  = (unsigned*)(ws + 400128);                // N*4  (dead after scans)
    unsigned short* Wt = (unsigned short*)(ws + 400128);         // 64KB, reuses counts space
    uint2*    edata   = (uint2*)(ws + 800256);                   // E*8
    unsigned short* z = (unsigned short*)(ws + 13600256);        // N*128*2
    float*    stats   = (float*)(ws + 39200256);                 // 256 f
    float*    ss      = (float*)(ws + 39201280);                 // 256 f
    unsigned* bsums   = (unsigned*)(ws + 39202304);              // 196*4
    unsigned* gbcur   = (unsigned*)(ws + 39203328);              // 391*4

    const int NB_SCAN = (N_NODES + 511) / 512;   // 196

    hipLaunchKernelGGL(k_zero, dim3((N_NODES + 255) / 256), dim3(256), 0, stream, counts, stats);
    hipLaunchKernelGGL(k_hist, dim3(2048), dim3(256), 0, stream, erow, counts);
    hipLaunchKernelGGL(k_scan_bsum, dim3(NB_SCAN), dim3(512), 0, stream, counts, bsums);
    hipLaunchKernelGGL(k_scan_top, dim3(1), dim3(256), 0, stream, bsums, NB_SCAN);
    hipLaunchKernelGGL(k_scan_apply, dim3(NB_SCAN), dim3(512), 0, stream, counts, bsums, row_ptr);
    hipLaunchKernelGGL(k_prep, dim3(128), dim3(256), 0, stream, W, Wt, row_ptr, gbcur);
    hipLaunchKernelGGL(k_binA, dim3(NCHUNK), dim3(256), 0, stream, erow, ecol, edge_w, gbcur, edata);
    hipLaunchKernelGGL(k_binB, dim3(NBKT), dim3(256), 0, stream, row_ptr, edata);
    hipLaunchKernelGGL(k_gemm, dim3((N_NODES + 63) / 64), dim3(256), 0, stream, x, Wt, b, z, out);
    hipLaunchKernelGGL(k_agg, dim3(N_NODES / 4), dim3(256), 0, stream, row_ptr, edata,
                       (const unsigned*)z, out);
    hipLaunchKernelGGL(k_stats, dim3(1024), dim3(256), 0, stream, out, stats);
    hipLaunchKernelGGL(k_finalize, dim3(1), dim3(128), 0, stream, stats, gamma, beta, ss);
    hipLaunchKernelGGL(k_apply, dim3(2048), dim3(256), 0, stream, out, ss);
}